// Round 7
// baseline (270.428 us; speedup 1.0000x reference)
//
#include <hip/hip_runtime.h>
#include <hip/hip_bf16.h>

#define NBANDS 31
#define CDIM 128
#define TDIM 2000
#define HDIM 512
#define MTOT 8000
#define MAXO 204
#define OPAD 224       // b2 bias padded length
#define NGRP 124
#define NMTB 63        // 128-row m-blocks per band
#define NMTILE 504     // padded 16-row m-tiles per band

typedef __attribute__((ext_vector_type(8))) short short8;
typedef __attribute__((ext_vector_type(4))) float f32x4;
typedef __attribute__((ext_vector_type(4))) unsigned int u32x4;
typedef __bf16 bf16x8 __attribute__((ext_vector_type(8)));

__constant__ int d_bw[NBANDS]   = {2,3,3,3,3,3,3,3,3,3,3,8,8,8,8,8,8,8,8,8,8,8,8,16,16,16,16,16,16,16,17};
__constant__ int d_boff[NBANDS] = {0,2,5,8,11,14,17,20,23,26,29,32,40,48,56,64,72,80,88,96,104,112,120,128,144,160,176,192,208,224,240};
__constant__ int d_nn16[NBANDS] = {2,3,3,3,3,3,3,3,3,3,3,6,6,6,6,6,6,6,6,6,6,6,6,12,12,12,12,12,12,12,13};

__device__ __forceinline__ unsigned short f2bf(float f) {
  unsigned int u = __float_as_uint(f);
  return (unsigned short)((u + 0x7fffu + ((u >> 16) & 1u)) >> 16);
}

// packed f32x2 -> bf16x2 (RNE); no builtin on gfx950 (T12)
__device__ __forceinline__ unsigned int cvt_pk_bf16(float lo, float hi) {
  unsigned int r;
  asm("v_cvt_pk_bf16_f32 %0, %1, %2" : "=v"(r) : "v"(lo), "v"(hi));
  return r;
}

// tanh(x) = 1 - 2/(exp2(2*log2e*x)+1)
__device__ __forceinline__ float fast_tanh(float x) {
  float p = __builtin_amdgcn_exp2f(2.885390082f * x);
  return 1.0f - 2.0f * __builtin_amdgcn_rcpf(p + 1.0f);
}

__device__ __forceinline__ float fast_sigmoid(float x) {
  return __builtin_amdgcn_rcpf(1.0f + __builtin_amdgcn_exp2f(-1.442695041f * x));
}

__device__ __forceinline__ f32x4 mfma_bf16(short8 a, short8 b, f32x4 c) {
  return __builtin_amdgcn_mfma_f32_16x16x32_bf16(
      __builtin_bit_cast(bf16x8, a), __builtin_bit_cast(bf16x8, b), c, 0, 0, 0);
}

// ------------- finalize group stats -------------
__global__ void k_finalize(const float* __restrict__ wsum, const float* __restrict__ wsq,
                           float* __restrict__ gmean, float* __restrict__ grstd) {
  int g = threadIdx.x;
  if (g < NGRP) {
    const float n = (float)(CDIM * TDIM);
    float m = wsum[g] / n;
    float v = wsq[g] / n - m * m;
    gmean[g] = m;
    grstd[g] = rsqrtf(v + 1e-5f);
  }
}

// ------------- prep fc1: fold norm affine, MFMA-A fragment order ------------
// w1f: [k][nc 4][hh 8][kk 4][lane 64][8e]; lane l = (h&15)|(q<<4) holds
//   W1fold[h][c = kk*32 + q*8 + j]
__global__ void k_prep_w1(const float* __restrict__ fc1_w, const float* __restrict__ norm_w,
                          const float* __restrict__ norm_b, const float* __restrict__ fc1_b,
                          unsigned short* __restrict__ w1f, float* __restrict__ t1,
                          float* __restrict__ t2) {
  int kn = blockIdx.x;              // k*512 + n(h)
  int k = kn >> 9, n = kn & 511;
  int c = threadIdx.x;              // 128 threads
  float w  = fc1_w[(size_t)kn * CDIM + c];
  float nw = norm_w[k * CDIM + c];
  float nb = norm_b[k * CDIM + c];
  float wp = w * nw;
  {
    int nc = n >> 7, hh = (n >> 4) & 7, kk = c >> 5;
    int lnw = (n & 15) | (((c >> 3) & 3) << 4);
    size_t eoff = ((((size_t)(k * 4 + nc) * 8 + hh) * 4 + kk) * 64 + lnw) * 8 + (c & 7);
    w1f[eoff] = f2bf(wp);
  }
  float s1 = wp, s2 = w * nb;
  #pragma unroll
  for (int off = 32; off >= 1; off >>= 1) {
    s1 += __shfl_down(s1, off);
    s2 += __shfl_down(s2, off);
  }
  __shared__ float r1[2], r2[2];
  if ((threadIdx.x & 63) == 0) { r1[threadIdx.x >> 6] = s1; r2[threadIdx.x >> 6] = s2; }
  __syncthreads();
  if (threadIdx.x == 0) {
    t1[kn] = r1[0] + r1[1];
    t2[kn] = r2[0] + r2[1] + fc1_b[kn];
  }
}

// ------------- prep fc2: GLU-pair permute + pi(k) column permute ------------
// w2f: [k][ks 16][ot 16][lane 64][8e].  Within each 32-h k-step the column
// order is pi(k) = ((k>>2)&1)*16 + (k>>3)*4 + (k&3), matching fc1's C-frag
// (lane q4 holds h = q4*4+r of h-tiles ht0/ht1) consumed directly as B-frag.
__global__ void k_prep_w2(const float* __restrict__ fc2_w, const float* __restrict__ fc2_b,
                          unsigned short* __restrict__ w2f, float* __restrict__ b2) {
  int ko = blockIdx.x;              // k*256 + o
  int k = ko >> 8;
  int o = ko & 255;
  int bw = d_bw[k];
  int O2 = 12 * bw, hf = 6 * bw;
  bool valid = o < O2;
  int srcrow = valid ? ((o & 1) ? (hf + (o >> 1)) : (o >> 1)) : 0;
  const float* sp = fc2_w + ((size_t)k * MAXO + srcrow) * HDIM;
  if (threadIdx.x == 0 && o < OPAD)
    b2[k * OPAD + o] = valid ? fc2_b[k * MAXO + srcrow] : 0.f;
  int ot = o >> 4, rr = o & 15;
  for (int j = threadIdx.x; j < HDIM; j += 256) {
    int ks = j >> 5, hp = j & 31;
    int q  = (hp >> 2) & 3;                 // inverse of pi: lane quad
    int jj = ((hp >> 4) << 2) | (hp & 3);   // elem = ht*4 + r
    unsigned short val = valid ? f2bf(sp[j]) : (unsigned short)0;
    size_t eoff = (((size_t)(k * 16 + ks)) * 16 + ot) * 512 + (size_t)(rr | (q << 4)) * 8 + jj;
    w2f[eoff] = val;
  }
}

// ------------- transpose x[B,C,T,K] -> xtf fragment order, fused stats ------
__global__ void k_transpose(const float* __restrict__ x, unsigned short* __restrict__ xtf,
                            float* __restrict__ wsum, float* __restrict__ wsq) {
  __shared__ unsigned short tile[248 * 128];   // rows staggered by 4f bytes
  __shared__ float sred[256], sqred[256];
  const int t0 = blockIdx.x * 8;
  const int b = blockIdx.y;
  const int tid = threadIdx.x;
  const float* p = x + ((size_t)b * CDIM * TDIM + t0) * NBANDS;
  float s = 0.f, sq = 0.f;
  if (tid < 248) {
    const int f = tid;
    char* row = (char*)tile + f * 256;
    const int st = 4 * f;
    #pragma unroll 4
    for (int c2 = 0; c2 < 64; ++c2) {
      float v0 = p[(size_t)c2 * 124000 + f];
      float v1 = p[(size_t)c2 * 124000 + 62000 + f];
      s += v0 + v1;
      sq += v0 * v0 + v1 * v1;
      *(unsigned int*)(row + ((4 * c2 + st) & 255)) = cvt_pk_bf16(v0, v1);
    }
  }
  sred[tid] = s; sqred[tid] = sq;
  __syncthreads();
  if (tid < 31) {
    float ss = 0.f, qs = 0.f;
    #pragma unroll
    for (int j = 0; j < 8; ++j) { ss += sred[tid + 31 * j]; qs += sqred[tid + 31 * j]; }
    atomicAdd(&wsum[b * 31 + tid], ss);
    atomicAdd(&wsq [b * 31 + tid], qs);
  }
  for (int idx = tid; idx < 3968; idx += 256) {
    int ti = idx & 7, q4w = (idx >> 3) & 3, kkw = (idx >> 5) & 3, kb = idx >> 7;
    int f = ti * 31 + kb;
    const char* row = (const char*)tile + f * 256;
    const int st = 4 * f;
    u32x4 v;
    #pragma unroll
    for (int j = 0; j < 4; ++j)
      v[j] = *(const unsigned int*)(row + ((kkw * 64 + q4w * 16 + 4 * j + st) & 255));
    int m = b * TDIM + t0 + ti;
    int mtile = m >> 4, mrow = m & 15;
    size_t eoff = ((((size_t)kb * NMTILE + mtile) * 4 + kkw) * 64 + (mrow | (q4w << 4))) * 8;
    *(u32x4*)(xtf + eoff) = v;
  }
}

// ------------- fused GEMM: barrier-free, wave-independent -------------------
// Each wave owns 32 m-rows for the full fc1->tanh->fc2->GLU chain.  fc1 C-frag
// is consumed directly as fc2 B-frag via the pi(k) column permute baked into
// w2f.  No LDS / no __syncthreads in the main loop.  SMAX = max o-tiles of the
// band class (3 / 6 / 13) so small-band classes keep acc2 tiny.
template<int SMAX>
__launch_bounds__(256, 2)
__global__ void k_gemm(const unsigned short* __restrict__ xtf,
                       const unsigned short* __restrict__ w1f,
                       const float* __restrict__ t1p, const float* __restrict__ t2p,
                       const unsigned short* __restrict__ w2f,
                       const float* __restrict__ b2p,
                       const float* __restrict__ gmean, const float* __restrict__ grstd,
                       float* __restrict__ out, int kbase, int nwg) {
  extern __shared__ float Ls[];

  // bijective XCD-aware swizzle
  const int bid = blockIdx.x;
  const int qq = nwg >> 3, r8 = nwg & 7;
  const int xcd = bid & 7, ixd = bid >> 3;
  const int wg = (xcd < r8 ? xcd * (qq + 1) : r8 * (qq + 1) + (xcd - r8) * qq) + ixd;
  const int kl = wg / NMTB;
  const int k = kbase + kl;
  const int mtb = wg - kl * NMTB;
  const int m0 = mtb * 128;

  const int tid = threadIdx.x;
  const int lane = tid & 63;
  const int wid = tid >> 6;          // 4 waves, 32 m-rows each
  const int col = lane & 15;
  const int q4 = lane >> 4;

  const int bw = d_bw[k];
  const int nn = d_nn16[k];          // <= SMAX
  const int half = 6 * bw;
  const int boffk = d_boff[k];

  // X fragments held in registers for the whole kernel (32 VGPR, zero re-reads)
  const int mt0 = (m0 >> 4) + wid * 2;
  short8 xv[2][4];
  #pragma unroll
  for (int m2 = 0; m2 < 2; ++m2)
    #pragma unroll
    for (int kk = 0; kk < 4; ++kk)
      xv[m2][kk] = *(const short8*)(xtf +
          (((size_t)k * NMTILE + mt0 + m2) * 4 + kk) * 512 + lane * 8);

  // norm constants per m2 (acc col = m = lane&15)
  float rs2[2], rm2[2];
  #pragma unroll
  for (int m2 = 0; m2 < 2; ++m2) {
    int mr = m0 + wid * 32 + m2 * 16 + col;
    int mc = mr < (MTOT - 1) ? mr : (MTOT - 1);
    int g = (mc / 2000) * NBANDS + k;
    rs2[m2] = grstd[g];
    rm2[m2] = rs2[m2] * gmean[g];
  }

  const f32x4 fz = {0.f, 0.f, 0.f, 0.f};
  f32x4 acc2[SMAX][2];
  #pragma unroll
  for (int s = 0; s < SMAX; ++s) { acc2[s][0] = fz; acc2[s][1] = fz; }

  const float* t1k = t1p + k * HDIM + q4 * 4;
  const float* t2k = t2p + k * HDIM + q4 * 4;

  #pragma unroll 2
  for (int c = 0; c < 16; ++c) {     // 16 chunks of 32 h
    const unsigned short* w1b =
        w1f + ((size_t)(k * 4 + (c >> 2)) * 8 + (size_t)(c & 3) * 2) * 2048 + lane * 8;
    f32x4 a1[2][2];
    a1[0][0] = fz; a1[0][1] = fz; a1[1][0] = fz; a1[1][1] = fz;
    #pragma unroll
    for (int kk = 0; kk < 4; ++kk) {
      short8 wa0 = *(const short8*)(w1b + kk * 512);
      short8 wa1 = *(const short8*)(w1b + 2048 + kk * 512);
      a1[0][0] = mfma_bf16(wa0, xv[0][kk], a1[0][0]);
      a1[0][1] = mfma_bf16(wa0, xv[1][kk], a1[0][1]);
      a1[1][0] = mfma_bf16(wa1, xv[0][kk], a1[1][0]);
      a1[1][1] = mfma_bf16(wa1, xv[1][kk], a1[1][1]);
    }
    // tanh epilogue -> B-frag in-lane (pi(k) order), zero shuffles
    u32x4 hbw[2];
    #pragma unroll
    for (int ht = 0; ht < 2; ++ht) {
      const f32x4 c1 = *(const f32x4*)(t1k + c * 32 + ht * 16);
      const f32x4 c2 = *(const f32x4*)(t2k + c * 32 + ht * 16);
      #pragma unroll
      for (int m2 = 0; m2 < 2; ++m2) {
        f32x4 v = a1[ht][m2];
        float e0 = fast_tanh(fmaf(rs2[m2], v[0], fmaf(-rm2[m2], c1[0], c2[0])));
        float e1 = fast_tanh(fmaf(rs2[m2], v[1], fmaf(-rm2[m2], c1[1], c2[1])));
        float e2 = fast_tanh(fmaf(rs2[m2], v[2], fmaf(-rm2[m2], c1[2], c2[2])));
        float e3 = fast_tanh(fmaf(rs2[m2], v[3], fmaf(-rm2[m2], c1[3], c2[3])));
        hbw[m2][ht * 2]     = cvt_pk_bf16(e0, e1);
        hbw[m2][ht * 2 + 1] = cvt_pk_bf16(e2, e3);
      }
    }
    const short8 hb0 = __builtin_bit_cast(short8, hbw[0]);
    const short8 hb1 = __builtin_bit_cast(short8, hbw[1]);
    // fc2 partial over this 32-h chunk
    const unsigned short* w2b =
        w2f + ((size_t)(k * 16 + c) * 16) * 512 + lane * 8;
    #pragma unroll
    for (int s = 0; s < SMAX; ++s) {
      if (s < nn) {                  // wave-uniform branch
        short8 wb = *(const short8*)(w2b + s * 512);
        acc2[s][0] = mfma_bf16(wb, hb0, acc2[s][0]);
        acc2[s][1] = mfma_bf16(wb, hb1, acc2[s][1]);
      }
    }
  }

  // ---- GLU epilogue: pairs (a,g) are adjacent regs in-lane ----
  const float* b2k = b2p + (size_t)k * OPAD;
  const bool plain = ((m0 + 127) / 2000 == m0 / 2000) && (m0 + 128 <= MTOT);
  if (plain) {
    #pragma unroll
    for (int s = 0; s < SMAX; ++s) {
      if (s < nn) {
        f32x4 bias = *(const f32x4*)(b2k + s * 16 + q4 * 4);
        #pragma unroll
        for (int m2 = 0; m2 < 2; ++m2) {
          const int tloc = wid * 32 + m2 * 16 + col;
          f32x4 v = acc2[s][m2];
          #pragma unroll
          for (int p = 0; p < 2; ++p) {
            float a = v[2 * p] + bias[2 * p];
            float g = v[2 * p + 1] + bias[2 * p + 1];
            int op = s * 8 + q4 * 2 + p;
            if (op < half) {
              int orr = op / 6, occ = op - orr * 6;
              Ls[(orr * 128 + tloc) * 6 + occ] = a * fast_sigmoid(g);
            }
          }
        }
      }
    }
    __syncthreads();
    const int bb = m0 / 2000;
    const int tb = m0 - bb * 2000;
    const size_t obase = ((size_t)bb * 257 + boffk) * 2000;
    const int tot = bw * 384;          // u64 chunks
    for (int ii = tid; ii < tot; ii += 256) {
      int orr = ii / 384;
      int rem = ii - orr * 384;
      *(unsigned long long*)(out + (obase + (size_t)orr * 2000 + tb) * 6 + rem * 2) =
          *(const unsigned long long*)(Ls + orr * 768 + rem * 2);
    }
  } else {
    // boundary/tail blocks: scatter store
    #pragma unroll
    for (int s = 0; s < SMAX; ++s) {
      if (s < nn) {
        f32x4 bias = *(const f32x4*)(b2k + s * 16 + q4 * 4);
        #pragma unroll
        for (int m2 = 0; m2 < 2; ++m2) {
          const int m = m0 + wid * 32 + m2 * 16 + col;
          f32x4 v = acc2[s][m2];
          #pragma unroll
          for (int p = 0; p < 2; ++p) {
            float a = v[2 * p] + bias[2 * p];
            float g = v[2 * p + 1] + bias[2 * p + 1];
            int op = s * 8 + q4 * 2 + p;
            if (op < half && m < MTOT) {
              int bbm = m / 2000;
              int t = m - bbm * 2000;
              int orr = op / 6, occ = op - orr * 6;
              out[(((size_t)bbm * 257 + boffk + orr) * TDIM + t) * 6 + occ] =
                  a * fast_sigmoid(g);
            }
          }
        }
      }
    }
  }
}

extern "C" void kernel_launch(void* const* d_in, const int* in_sizes, int n_in,
                              void* d_out, int out_size, void* d_ws, size_t ws_size,
                              hipStream_t stream) {
  const float* x      = (const float*)d_in[0];
  const float* norm_w = (const float*)d_in[1];
  const float* norm_b = (const float*)d_in[2];
  const float* fc1_w  = (const float*)d_in[3];
  const float* fc1_b  = (const float*)d_in[4];
  const float* fc2_w  = (const float*)d_in[5];
  const float* fc2_b  = (const float*)d_in[6];
  float* out = (float*)d_out;
  char* ws = (char*)d_ws;

  float* wsum  = (float*)(ws);
  float* wsq   = (float*)(ws + 512);
  float* gmean = (float*)(ws + 1024);
  float* grstd = (float*)(ws + 1536);
  size_t off = 4096;
  unsigned short* xtf = (unsigned short*)(ws + off); off += (size_t)NBANDS * NMTILE * 4 * 512 * 2;
  unsigned short* w1f = (unsigned short*)(ws + off); off += (size_t)NBANDS * 4 * 8 * 4 * 512 * 2;
  float* t1p = (float*)(ws + off); off += (size_t)NBANDS * HDIM * 4;
  float* t2p = (float*)(ws + off); off += (size_t)NBANDS * HDIM * 4;
  unsigned short* w2f = (unsigned short*)(ws + off); off += (size_t)NBANDS * 16 * 16 * 512 * 2;
  float* b2p = (float*)(ws + off); off += (size_t)NBANDS * OPAD * 4;

  hipMemsetAsync(ws, 0, 1024, stream);
  hipLaunchKernelGGL(k_prep_w1, dim3(NBANDS * HDIM), dim3(128), 0, stream,
                     fc1_w, norm_w, norm_b, fc1_b, w1f, t1p, t2p);
  hipLaunchKernelGGL(k_prep_w2, dim3(NBANDS * 256), dim3(256), 0, stream,
                     fc2_w, fc2_b, w2f, b2p);
  hipLaunchKernelGGL(k_transpose, dim3(250, 4), dim3(256), 0, stream, x, xtf, wsum, wsq);
  hipLaunchKernelGGL(k_finalize, dim3(1), dim3(128), 0, stream, wsum, wsq, gmean, grstd);

  // band classes (contiguous): k 0..10 (nn<=3), 11..22 (nn=6), 23..30 (nn<=13)
  hipFuncSetAttribute((const void*)k_gemm<3>,  hipFuncAttributeMaxDynamicSharedMemorySize, 9216);
  hipFuncSetAttribute((const void*)k_gemm<6>,  hipFuncAttributeMaxDynamicSharedMemorySize, 24576);
  hipFuncSetAttribute((const void*)k_gemm<13>, hipFuncAttributeMaxDynamicSharedMemorySize, 52224);
  hipLaunchKernelGGL(k_gemm<3>,  dim3(11 * NMTB), dim3(256), 9216, stream,
                     xtf, w1f, t1p, t2p, w2f, b2p, gmean, grstd, out, 0,  11 * NMTB);
  hipLaunchKernelGGL(k_gemm<6>,  dim3(12 * NMTB), dim3(256), 24576, stream,
                     xtf, w1f, t1p, t2p, w2f, b2p, gmean, grstd, out, 11, 12 * NMTB);
  hipLaunchKernelGGL(k_gemm<13>, dim3(8 * NMTB),  dim3(256), 52224, stream,
                     xtf, w1f, t1p, t2p, w2f, b2p, gmean, grstd, out, 23, 8 * NMTB);
}